// Round 1
// baseline (173.225 us; speedup 1.0000x reference)
//
#include <hip/hip_runtime.h>

// Problem constants (fixed by setup_inputs: B=8, N=M=8192, D=3, fp32).
constexpr int BATCH  = 8;
constexpr int NPTS   = 8192;          // N == M
constexpr int TCHUNK = 1024;          // database points staged in LDS per block
constexpr int NSPLIT = NPTS / TCHUNK; // 8 database chunks (grid.z)
constexpr int BLOCK  = 256;
constexpr int IPT    = 4;             // queries per thread
constexpr int QPB    = BLOCK * IPT;   // 1024 queries per block
constexpr int QBLKS  = NPTS / QPB;    // 8 query blocks per direction

// Each block: stage TCHUNK database points (x,y,z,|p|^2) in LDS, each thread
// holds IPT query points in registers, computes d = |q|^2 + |t|^2 - 2 q.t
// (6 VALU instr/pair), keeps running min in registers, then combines across
// database chunks with a global atomicMin on the float bit pattern (valid for
// non-negative floats; mins are clamped to >= 0 before the atomic).
__global__ __launch_bounds__(BLOCK) void chamfer_nn_kernel(
    const float* __restrict__ src, const float* __restrict__ tgt,
    unsigned int* __restrict__ min_s2t, unsigned int* __restrict__ min_t2s)
{
    __shared__ float4 sh[TCHUNK];

    const int dir   = blockIdx.x / QBLKS;  // 0: queries=src, db=tgt ; 1: swapped
    const int xblk  = blockIdx.x % QBLKS;
    const int b     = blockIdx.y;
    const int chunk = blockIdx.z;

    const float* __restrict__ P = dir ? tgt : src;  // query points
    const float* __restrict__ Q = dir ? src : tgt;  // database points
    unsigned int* __restrict__ mout = dir ? min_t2s : min_s2t;

    // --- stage database chunk into LDS as (x, y, z, |p|^2) ---
    const float* dbase = Q + ((size_t)b * NPTS + (size_t)chunk * TCHUNK) * 3;
    for (int j = threadIdx.x; j < TCHUNK; j += BLOCK) {
        float x = dbase[3 * j + 0];
        float y = dbase[3 * j + 1];
        float z = dbase[3 * j + 2];
        sh[j] = make_float4(x, y, z, fmaf(x, x, fmaf(y, y, z * z)));
    }
    __syncthreads();

    // --- load my IPT query points ---
    float qx[IPT], qy[IPT], qz[IPT], qs[IPT], mn[IPT];
    int qidx[IPT];
#pragma unroll
    for (int i = 0; i < IPT; i++) {
        qidx[i] = xblk * QPB + i * BLOCK + (int)threadIdx.x;
        const float* p = P + ((size_t)b * NPTS + qidx[i]) * 3;
        qx[i] = p[0]; qy[i] = p[1]; qz[i] = p[2];
        qs[i] = fmaf(qx[i], qx[i], fmaf(qy[i], qy[i], qz[i] * qz[i]));
        mn[i] = 3.4e38f;
    }

    // --- main loop: 6 VALU instr per (query, db) pair ---
#pragma unroll 4
    for (int j = 0; j < TCHUNK; j++) {
        float4 t = sh[j];
#pragma unroll
        for (int i = 0; i < IPT; i++) {
            float dot = fmaf(qx[i], t.x, fmaf(qy[i], t.y, qz[i] * t.z));
            float d   = fmaf(-2.0f, dot, qs[i] + t.w);
            mn[i] = fminf(mn[i], d);
        }
    }

    // --- combine partial mins across database chunks ---
#pragma unroll
    for (int i = 0; i < IPT; i++) {
        unsigned int bits = __float_as_uint(fmaxf(mn[i], 0.0f));
        atomicMin(&mout[(size_t)b * NPTS + qidx[i]], bits);
    }
}

// One block per batch: mean of s2t mins + mean of t2s mins.
__global__ __launch_bounds__(256) void chamfer_reduce_kernel(
    const float* __restrict__ mins, float* __restrict__ out)
{
    const int b = blockIdx.x;
    float acc = 0.0f;
    for (int i = threadIdx.x; i < NPTS; i += 256) {
        acc += mins[(size_t)b * NPTS + i];                         // s2t
        acc += mins[(size_t)BATCH * NPTS + (size_t)b * NPTS + i];  // t2s
    }
    // wave (64-lane) shuffle reduction, then cross-wave via LDS
    for (int off = 32; off > 0; off >>= 1) acc += __shfl_down(acc, off, 64);
    __shared__ float wsum[BLOCK / 64];
    const int lane = threadIdx.x & 63;
    const int wid  = threadIdx.x >> 6;
    if (lane == 0) wsum[wid] = acc;
    __syncthreads();
    if (threadIdx.x == 0) {
        float s = wsum[0] + wsum[1] + wsum[2] + wsum[3];
        out[b] = s * (1.0f / (float)NPTS);
    }
}

extern "C" void kernel_launch(void* const* d_in, const int* in_sizes, int n_in,
                              void* d_out, int out_size, void* d_ws, size_t ws_size,
                              hipStream_t stream) {
    const float* src = (const float*)d_in[0];  // [B, N, 3]
    const float* tgt = (const float*)d_in[1];  // [B, M, 3]
    float* out = (float*)d_out;                // [B]

    unsigned int* mins = (unsigned int*)d_ws;  // [2, B, NPTS] float-as-uint
    const size_t min_bytes = (size_t)2 * BATCH * NPTS * sizeof(float);  // 512 KB

    // Init mins to a huge positive float (0x7f7f7f7f ~= 3.39e38). Workspace is
    // re-poisoned before every timed call, so this must run every launch.
    hipMemsetAsync(d_ws, 0x7f, min_bytes, stream);

    dim3 grid(2 * QBLKS, BATCH, NSPLIT);  // 16 x 8 x 8 = 1024 blocks
    chamfer_nn_kernel<<<grid, BLOCK, 0, stream>>>(
        src, tgt, mins, mins + (size_t)BATCH * NPTS);

    chamfer_reduce_kernel<<<BATCH, 256, 0, stream>>>((const float*)mins, out);
}

// Round 2
// 145.977 us; speedup vs baseline: 1.1867x; 1.1867x over previous
//
#include <hip/hip_runtime.h>

// Problem constants (fixed by setup_inputs: B=8, N=M=8192, D=3, fp32).
constexpr int BATCH  = 8;
constexpr int NPTS   = 8192;          // N == M
constexpr int TCHUNK = 512;           // database points staged in LDS per block
constexpr int NSPLIT = NPTS / TCHUNK; // 16 database chunks (grid.z)
constexpr int BLOCK  = 256;
constexpr int IPT    = 8;             // queries per thread
constexpr int QPB    = BLOCK * IPT;   // 2048 queries per block
constexpr int QBLKS  = NPTS / QPB;    // 4 query blocks per direction

// min over t of |q|^2+|t|^2-2q.t  ==  |q|^2 + 2 * min over t of (0.5|t|^2 - q.t).
// Stage (x,y,z,0.5|t|^2) in LDS; negate q once; inner body = 3 fma + 1 min
// = 4 VALU ops/pair. Each chunk writes its partial mins to a private slice of
// the workspace (no atomics, no init needed).
__global__ __launch_bounds__(BLOCK) void chamfer_nn_kernel(
    const float* __restrict__ src, const float* __restrict__ tgt,
    float* __restrict__ part)   // [2][BATCH][NSPLIT][NPTS]
{
    __shared__ float4 sh[TCHUNK];

    const int dir   = blockIdx.x / QBLKS;  // 0: queries=src, db=tgt ; 1: swapped
    const int xblk  = blockIdx.x % QBLKS;
    const int b     = blockIdx.y;
    const int chunk = blockIdx.z;

    const float* __restrict__ P = dir ? tgt : src;  // query points
    const float* __restrict__ Q = dir ? src : tgt;  // database points

    // --- stage database chunk into LDS as (x, y, z, 0.5*|p|^2) ---
    const float* dbase = Q + ((size_t)b * NPTS + (size_t)chunk * TCHUNK) * 3;
    for (int j = threadIdx.x; j < TCHUNK; j += BLOCK) {
        float x = dbase[3 * j + 0];
        float y = dbase[3 * j + 1];
        float z = dbase[3 * j + 2];
        sh[j] = make_float4(x, y, z, 0.5f * fmaf(x, x, fmaf(y, y, z * z)));
    }

    // --- load my IPT query points (negated coords) ---
    float qnx[IPT], qny[IPT], qnz[IPT], mn[IPT];
    const int q0 = xblk * QPB + (int)threadIdx.x;
    const float* pbase = P + (size_t)b * NPTS * 3;
#pragma unroll
    for (int i = 0; i < IPT; i++) {
        const float* p = pbase + (size_t)(q0 + i * BLOCK) * 3;
        qnx[i] = -p[0]; qny[i] = -p[1]; qnz[i] = -p[2];
        mn[i] = 3.4e38f;
    }
    __syncthreads();

    // --- main loop: 4 VALU instr per (query, db) pair ---
#pragma unroll 4
    for (int j = 0; j < TCHUNK; j++) {
        float4 t = sh[j];
#pragma unroll
        for (int i = 0; i < IPT; i++) {
            float v = fmaf(qnx[i], t.x,
                      fmaf(qny[i], t.y,
                      fmaf(qnz[i], t.z, t.w)));
            mn[i] = fminf(mn[i], v);
        }
    }

    // --- epilogue: d = |q|^2 + 2*v_min ; coalesced store to private slice ---
    float* pout = part + (((size_t)dir * BATCH + b) * NSPLIT + chunk) * NPTS;
#pragma unroll
    for (int i = 0; i < IPT; i++) {
        float qs = fmaf(qnx[i], qnx[i], fmaf(qny[i], qny[i], qnz[i] * qnz[i]));
        pout[q0 + i * BLOCK] = fmaf(2.0f, mn[i], qs);
    }
}

// One block per batch: min over NSPLIT chunks, sum over queries, both dirs.
__global__ __launch_bounds__(1024) void chamfer_reduce_kernel(
    const float* __restrict__ part, float* __restrict__ out)
{
    const int b = blockIdx.x;
    float acc = 0.0f;
    for (int dir = 0; dir < 2; dir++) {
        const float* p = part + ((size_t)dir * BATCH + b) * NSPLIT * NPTS;
        for (int q = threadIdx.x; q < NPTS; q += 1024) {
            float m = p[q];
#pragma unroll
            for (int c = 1; c < NSPLIT; c++) m = fminf(m, p[(size_t)c * NPTS + q]);
            acc += m;
        }
    }
    // wave (64-lane) shuffle reduction, then cross-wave via LDS
    for (int off = 32; off > 0; off >>= 1) acc += __shfl_down(acc, off, 64);
    __shared__ float wsum[16];
    const int lane = threadIdx.x & 63;
    const int wid  = threadIdx.x >> 6;
    if (lane == 0) wsum[wid] = acc;
    __syncthreads();
    if (threadIdx.x < 64) {
        float s = (threadIdx.x < 16) ? wsum[threadIdx.x] : 0.0f;
        for (int off = 8; off > 0; off >>= 1) s += __shfl_down(s, off, 64);
        if (threadIdx.x == 0) out[b] = s * (1.0f / (float)NPTS);
    }
}

extern "C" void kernel_launch(void* const* d_in, const int* in_sizes, int n_in,
                              void* d_out, int out_size, void* d_ws, size_t ws_size,
                              hipStream_t stream) {
    const float* src = (const float*)d_in[0];  // [B, N, 3]
    const float* tgt = (const float*)d_in[1];  // [B, M, 3]
    float* out = (float*)d_out;                // [B]
    float* part = (float*)d_ws;                // [2][B][NSPLIT][NPTS] = 8 MB

    dim3 grid(2 * QBLKS, BATCH, NSPLIT);  // 8 x 8 x 16 = 1024 blocks
    chamfer_nn_kernel<<<grid, BLOCK, 0, stream>>>(src, tgt, part);

    chamfer_reduce_kernel<<<BATCH, 1024, 0, stream>>>(part, out);
}

// Round 5
// 137.276 us; speedup vs baseline: 1.2619x; 1.0634x over previous
//
#include <hip/hip_runtime.h>

// Problem constants (fixed by setup_inputs: B=8, N=M=8192, D=3, fp32).
constexpr int BATCH  = 8;
constexpr int NPTS   = 8192;          // N == M
constexpr int TCHUNK = 256;           // database points staged in LDS per block
constexpr int NSPLIT = NPTS / TCHUNK; // 32 database chunks (grid.z)
constexpr int BLOCK  = 256;
constexpr int IPT    = 8;             // queries per thread
constexpr int QPB    = BLOCK * IPT;   // 2048 queries per block
constexpr int QBLKS  = NPTS / QPB;    // 4 query blocks per direction

// min over t of |q|^2+|t|^2-2q.t  ==  |q|^2 + 2 * min over t of (0.5|t|^2 - q.t).
// Stage (x,y,z,0.5|t|^2) in LDS; negate q once; inner body = 3 fma + 1 min
// = 4 VALU ops/pair. Partial mins across the NSPLIT database chunks combine
// via atomicMin on the float bit pattern (valid for non-negative floats;
// results are clamped >= 0). Workspace use: only 512 KB (R1-proven safe).
// NSPLIT=32 -> 2048 blocks -> 8 blocks/CU -> 32 waves/CU (VGPR=36 <= 64).
__global__ __launch_bounds__(BLOCK) void chamfer_nn_kernel(
    const float* __restrict__ src, const float* __restrict__ tgt,
    unsigned int* __restrict__ mins)   // [2][BATCH][NPTS] float-as-uint
{
    __shared__ float4 sh[TCHUNK];

    const int dir   = blockIdx.x / QBLKS;  // 0: queries=src, db=tgt ; 1: swapped
    const int xblk  = blockIdx.x % QBLKS;
    const int b     = blockIdx.y;
    const int chunk = blockIdx.z;

    const float* __restrict__ P = dir ? tgt : src;  // query points
    const float* __restrict__ Q = dir ? src : tgt;  // database points

    // --- stage database chunk into LDS as (x, y, z, 0.5*|p|^2) ---
    {
        const float* dbase = Q + ((size_t)b * NPTS + (size_t)chunk * TCHUNK) * 3;
        const int j = threadIdx.x;  // BLOCK == TCHUNK
        float x = dbase[3 * j + 0];
        float y = dbase[3 * j + 1];
        float z = dbase[3 * j + 2];
        sh[j] = make_float4(x, y, z, 0.5f * fmaf(x, x, fmaf(y, y, z * z)));
    }

    // --- load my IPT query points (negated coords) ---
    float qnx[IPT], qny[IPT], qnz[IPT], mn[IPT];
    const int q0 = xblk * QPB + (int)threadIdx.x;
    const float* pbase = P + (size_t)b * NPTS * 3;
#pragma unroll
    for (int i = 0; i < IPT; i++) {
        const float* p = pbase + (size_t)(q0 + i * BLOCK) * 3;
        qnx[i] = -p[0]; qny[i] = -p[1]; qnz[i] = -p[2];
        mn[i] = 3.4e38f;
    }
    __syncthreads();

    // --- main loop: 4 VALU instr per (query, db) pair ---
#pragma unroll 4
    for (int j = 0; j < TCHUNK; j++) {
        float4 t = sh[j];
#pragma unroll
        for (int i = 0; i < IPT; i++) {
            float v = fmaf(qnx[i], t.x,
                      fmaf(qny[i], t.y,
                      fmaf(qnz[i], t.z, t.w)));
            mn[i] = fminf(mn[i], v);
        }
    }

    // --- epilogue: d = max(|q|^2 + 2*v_min, 0); combine chunks via atomicMin
    unsigned int* mout = mins + ((size_t)dir * BATCH + b) * NPTS;
#pragma unroll
    for (int i = 0; i < IPT; i++) {
        float qs = fmaf(qnx[i], qnx[i], fmaf(qny[i], qny[i], qnz[i] * qnz[i]));
        float d  = fmaxf(fmaf(2.0f, mn[i], qs), 0.0f);
        atomicMin(&mout[q0 + i * BLOCK], __float_as_uint(d));
    }
}

// One block per batch (1024 threads): sum final mins for both directions.
// Only 512 KB total input, L2-resident -> ~1 us. Deterministic, no atomics.
__global__ __launch_bounds__(1024) void chamfer_out_kernel(
    const unsigned int* __restrict__ mins, float* __restrict__ out)
{
    const int b = blockIdx.x;
    float acc = 0.0f;
    for (int dir = 0; dir < 2; dir++) {
        const unsigned int* p = mins + ((size_t)dir * BATCH + b) * NPTS;
        for (int q = threadIdx.x; q < NPTS; q += 1024)
            acc += __uint_as_float(p[q]);
    }
    // wave (64-lane) shuffle reduction, then cross-wave via LDS
    for (int off = 32; off > 0; off >>= 1) acc += __shfl_down(acc, off, 64);
    __shared__ float wsum[16];
    const int lane = threadIdx.x & 63;
    const int wid  = threadIdx.x >> 6;
    if (lane == 0) wsum[wid] = acc;
    __syncthreads();
    if (threadIdx.x < 64) {
        float s = (threadIdx.x < 16) ? wsum[threadIdx.x] : 0.0f;
        for (int off = 8; off > 0; off >>= 1) s += __shfl_down(s, off, 64);
        if (threadIdx.x == 0) out[b] = s * (1.0f / (float)NPTS);
    }
}

extern "C" void kernel_launch(void* const* d_in, const int* in_sizes, int n_in,
                              void* d_out, int out_size, void* d_ws, size_t ws_size,
                              hipStream_t stream) {
    const float* src = (const float*)d_in[0];  // [B, N, 3]
    const float* tgt = (const float*)d_in[1];  // [B, M, 3]
    float* out = (float*)d_out;                // [B]

    unsigned int* mins = (unsigned int*)d_ws;  // [2][B][NPTS] = 512 KB
    const size_t min_bytes = (size_t)2 * BATCH * NPTS * sizeof(float);

    // Init mins to a huge positive float (0x7f7f7f7f ~= 3.39e38). Workspace is
    // re-poisoned before every timed call, so this must run every launch.
    hipMemsetAsync(d_ws, 0x7f, min_bytes, stream);

    dim3 grid(2 * QBLKS, BATCH, NSPLIT);  // 8 x 8 x 32 = 2048 blocks
    chamfer_nn_kernel<<<grid, BLOCK, 0, stream>>>(src, tgt, mins);

    chamfer_out_kernel<<<BATCH, 1024, 0, stream>>>(mins, out);
}